// Round 1
// baseline (450.392 us; speedup 1.0000x reference)
//
#include <hip/hip_runtime.h>

#define NEG_INF -9e15f
#define ALPHA 0.2f

// One block per row n. K=32 neighbors, D=100 features.
// We = entity*w_r kept in LDS (12.8 KB); softmax over K; weighted sum; D x D
// matmul epilogue with residual. Memory-bound: 1.07 GB HBM traffic/call.
__global__ __launch_bounds__(256) void gat_fused_kernel(
    const float* __restrict__ item,   // [N, D]
    const float* __restrict__ ent,    // [N, K, D]
    const float* __restrict__ wr,     // [N, K, D]
    const int*   __restrict__ adj,    // [N, K]
    const float* __restrict__ Wout,   // [D, D]
    const float* __restrict__ bout,   // [D]
    float* __restrict__ out)          // [N, D]
{
    constexpr int K = 32, D = 100;
    const int n = blockIdx.x;
    const int t = threadIdx.x;

    __shared__ float sWe[K * D];   // 12800 B
    __shared__ float sSum[K];
    __shared__ float sAtt[K];
    __shared__ float sH[D];

    if (t < K) sSum[t] = 0.0f;
    __syncthreads();

    // ---- Phase 1: vectorized load, We = e*w into LDS, per-k partial sums ----
    // K*D = 3200 floats = 800 float4; each k-row is exactly 25 float4s.
    const float4* e4 = reinterpret_cast<const float4*>(ent + (size_t)n * (K * D));
    const float4* w4 = reinterpret_cast<const float4*>(wr  + (size_t)n * (K * D));
    float4* sWe4 = reinterpret_cast<float4*>(sWe);
    for (int i = t; i < (K * D) / 4; i += 256) {
        float4 a = e4[i];
        float4 b = w4[i];
        float4 p;
        p.x = a.x * b.x; p.y = a.y * b.y; p.z = a.z * b.z; p.w = a.w * b.w;
        sWe4[i] = p;
        atomicAdd(&sSum[i / (D / 4)], p.x + p.y + p.z + p.w);
    }
    __syncthreads();

    // ---- Phase 2: leaky-relu + mask + softmax over K (lanes 0..31, wave 0) ----
    if (t < K) {
        float s = sSum[t];
        float e = s > 0.0f ? s : ALPHA * s;
        float lg = adj[(size_t)n * K + t] > 0 ? e : NEG_INF;
        float m = lg;
        #pragma unroll
        for (int off = 16; off; off >>= 1)
            m = fmaxf(m, __shfl_xor(m, off, K));
        float p = expf(lg - m);
        float sm = p;
        #pragma unroll
        for (int off = 16; off; off >>= 1)
            sm += __shfl_xor(sm, off, K);
        sAtt[t] = p / sm;
    }
    __syncthreads();

    // ---- Phase 3: h_prime[d] = sum_k att[k] * We[k][d] ----
    if (t < D) {
        float h = 0.0f;
        #pragma unroll
        for (int k = 0; k < K; ++k)
            h = fmaf(sAtt[k], sWe[k * D + t], h);
        sH[t] = h;
    }
    __syncthreads();

    // ---- Phase 4: out[d] = sum_j h[j] * Wout[d][j] + b[d] + item[d] ----
    if (t < D) {
        float acc = bout[t];
        const float* wrow = Wout + (size_t)t * D;
        #pragma unroll 4
        for (int j = 0; j < D; ++j)
            acc = fmaf(sH[j], wrow[j], acc);
        out[(size_t)n * D + t] = acc + item[(size_t)n * D + t];
    }
}

extern "C" void kernel_launch(void* const* d_in, const int* in_sizes, int n_in,
                              void* d_out, int out_size, void* d_ws, size_t ws_size,
                              hipStream_t stream) {
    const float* item = (const float*)d_in[0];
    const float* ent  = (const float*)d_in[1];
    const float* wr   = (const float*)d_in[2];
    const int*   adj  = (const int*)d_in[3];
    const float* Wout = (const float*)d_in[4];
    const float* bout = (const float*)d_in[5];
    float* out = (float*)d_out;

    const int N = 40000;
    gat_fused_kernel<<<N, 256, 0, stream>>>(item, ent, wr, adj, Wout, bout, out);
}

// Round 2
// 359.104 us; speedup vs baseline: 1.2542x; 1.2542x over previous
//
#include <hip/hip_runtime.h>

#define NEG_INF -9e15f
#define ALPHA 0.2f

// K=32 neighbors, D=100 features, N=40000 rows.
// Persistent-block pipelined version: 2048 blocks x 256 threads, each block
// grid-strides over rows. Next row's global loads (ent/wr/adj/item) are issued
// immediately after the current row's registers are stored to LDS, so HBM
// latency overlaps the softmax/matvec phases. 3 __syncthreads per row.
constexpr int K = 32, D = 100, KD = K * D;   // KD = 3200 floats, 800 float4
constexpr int NBLK = 2048;                   // 256 CU x 8 blocks

__global__ __launch_bounds__(256) void gat_fused_pipe(
    const float* __restrict__ item,   // [N, D]
    const float* __restrict__ ent,    // [N, K, D]
    const float* __restrict__ wr,     // [N, K, D]
    const int*   __restrict__ adj,    // [N, K]
    const float* __restrict__ Wout,   // [D, D]
    const float* __restrict__ bout,   // [D]
    float* __restrict__ out,          // [N, D]
    int N)
{
    const int t = threadIdx.x;
    __shared__ float sWe[KD];     // 12.8 KB
    __shared__ float sSum[K];
    __shared__ float sAtt[K];
    __shared__ float sH[D];
    float4* sWe4 = reinterpret_cast<float4*>(sWe);

    const int d = t >> 1;
    const int half = t & 1;
    const bool dt = (t < 2 * D);           // 200 worker threads for phases 3/4

    float pbout = 0.f;
    if (dt && !half) pbout = bout[d];      // loop-invariant

    int n = blockIdx.x;

    // ---- initial prefetch of row n into registers ----
    float4 pa0, pa1, pa2, pa3, pb0, pb1, pb2, pb3;
    float pitem = 0.f;
    int   padj  = 0;
    {
        const float4* e4 = reinterpret_cast<const float4*>(ent + (size_t)n * KD);
        const float4* w4 = reinterpret_cast<const float4*>(wr  + (size_t)n * KD);
        pa0 = e4[t];       pb0 = w4[t];
        pa1 = e4[t + 256]; pb1 = w4[t + 256];
        pa2 = e4[t + 512]; pb2 = w4[t + 512];
        if (t < 32) { pa3 = e4[t + 768]; pb3 = w4[t + 768]; }
        if (t < K)        padj  = adj[(size_t)n * K + t];
        if (dt && !half)  pitem = item[(size_t)n * D + d];
    }
    if (t < K) sSum[t] = 0.f;
    __syncthreads();

#define PHASE1_STEP(PA, PB, OFF) do {                                      \
        float4 p;                                                          \
        p.x = PA.x * PB.x; p.y = PA.y * PB.y;                              \
        p.z = PA.z * PB.z; p.w = PA.w * PB.w;                              \
        sWe4[t + (OFF)] = p;                                               \
        atomicAdd(&sSum[(t + (OFF)) / 25], (p.x + p.y) + (p.z + p.w));     \
    } while (0)

    for (;;) {
        // ---- phase 1: We -> LDS, per-k sums via LDS atomics ----
        PHASE1_STEP(pa0, pb0, 0);
        PHASE1_STEP(pa1, pb1, 256);
        PHASE1_STEP(pa2, pb2, 512);
        if (t < 32) PHASE1_STEP(pa3, pb3, 768);

        // ---- issue prefetch for the NEXT row (overlaps phases 2-4) ----
        const int n2 = n + NBLK;
        const bool more = (n2 < N);
        float nitem = 0.f;
        int   nadj  = 0;
        if (more) {
            const float4* e4 = reinterpret_cast<const float4*>(ent + (size_t)n2 * KD);
            const float4* w4 = reinterpret_cast<const float4*>(wr  + (size_t)n2 * KD);
            pa0 = e4[t];       pb0 = w4[t];
            pa1 = e4[t + 256]; pb1 = w4[t + 256];
            pa2 = e4[t + 512]; pb2 = w4[t + 512];
            if (t < 32) { pa3 = e4[t + 768]; pb3 = w4[t + 768]; }
            if (t < K)        nadj  = adj[(size_t)n2 * K + t];
            if (dt && !half)  nitem = item[(size_t)n2 * D + d];
        }
        __syncthreads();   // sync1: sWe + sSum ready

        // ---- phase 2: leaky-relu + mask + softmax over K (wave 0) ----
        if (t < K) {
            float s = sSum[t];
            sSum[t] = 0.f;                       // reset for next row
            float e  = s > 0.f ? s : ALPHA * s;
            float lg = padj > 0 ? e : NEG_INF;
            float m = lg;
            #pragma unroll
            for (int off = 16; off; off >>= 1)
                m = fmaxf(m, __shfl_xor(m, off, 32));
            float p = expf(lg - m);
            float sm = p;
            #pragma unroll
            for (int off = 16; off; off >>= 1)
                sm += __shfl_xor(sm, off, 32);
            sAtt[t] = p / sm;
        }
        __syncthreads();   // sync2: sAtt ready

        // ---- phase 3: h[d] = sum_k att[k]*We[k][d], split-K over 2 lanes ----
        if (dt) {
            const int k0 = half * 16;
            float h = 0.f;
            #pragma unroll
            for (int kk = 0; kk < 16; ++kk)
                h = fmaf(sAtt[k0 + kk], sWe[(k0 + kk) * D + d], h);
            h += __shfl_xor(h, 1, 64);
            if (!half) sH[d] = h;
        }
        __syncthreads();   // sync3: sH ready

        // ---- phase 4: out[d] = h . Wout[d,:] + b[d] + item[d], split-J ----
        if (dt) {
            const float* wrow = Wout + (size_t)d * D + half * 50;
            const float* hh   = sH + half * 50;
            float acc = 0.f;
            #pragma unroll
            for (int j = 0; j < 50; ++j)
                acc = fmaf(hh[j], wrow[j], acc);
            acc += __shfl_xor(acc, 1, 64);
            if (!half) out[(size_t)n * D + d] = acc + pbout + pitem;
        }

        if (!more) break;
        n = n2;
        pitem = nitem;
        padj  = nadj;
    }
#undef PHASE1_STEP
}

extern "C" void kernel_launch(void* const* d_in, const int* in_sizes, int n_in,
                              void* d_out, int out_size, void* d_ws, size_t ws_size,
                              hipStream_t stream) {
    const float* item = (const float*)d_in[0];
    const float* ent  = (const float*)d_in[1];
    const float* wr   = (const float*)d_in[2];
    const int*   adj  = (const int*)d_in[3];
    const float* Wout = (const float*)d_in[4];
    const float* bout = (const float*)d_in[5];
    float* out = (float*)d_out;

    const int N = 40000;
    gat_fused_pipe<<<NBLK, 256, 0, stream>>>(item, ent, wr, adj, Wout, bout, out, N);
}

// Round 3
// 323.037 us; speedup vs baseline: 1.3942x; 1.1117x over previous
//
#include <hip/hip_runtime.h>

#define NEG_INF -9e15f
#define ALPHA 0.2f

// K=32 neighbors, D=100 features, N=40000 rows.
// Persistent blocks, register prefetch of next row, and RAW barriers
// (lgkmcnt-only) so prefetch global loads are NOT drained at the barrier
// (__syncthreads would emit s_waitcnt vmcnt(0) -- the documented barrier
// drain). Phase-1 per-k sums via shfl (no LDS atomics).
constexpr int K = 32, D = 100, KD = K * D;   // 3200 floats = 800 float4
constexpr int NBLK = 2048;                   // 256 CU x 8 blocks

// LDS-ordering barrier that does NOT drain vmcnt: prefetch loads stay in
// flight across it. "memory" clobbers pin LDS ops and the load issue point.
__device__ __forceinline__ void ldsbar() {
    asm volatile("s_waitcnt lgkmcnt(0)" ::: "memory");
    __builtin_amdgcn_s_barrier();
    asm volatile("" ::: "memory");
}

__global__ __launch_bounds__(256) void gat_fused_pipe(
    const float* __restrict__ item,   // [N, D]
    const float* __restrict__ ent,    // [N, K, D]
    const float* __restrict__ wr,     // [N, K, D]
    const int*   __restrict__ adj,    // [N, K]
    const float* __restrict__ Wout,   // [D, D]
    const float* __restrict__ bout,   // [D]
    float* __restrict__ out,          // [N, D]
    int N)
{
    const int t = threadIdx.x;
    __shared__ float sWe[KD];     // 12.8 KB
    __shared__ float sSum[K];
    __shared__ float sAtt[K];
    __shared__ float sH[D];
    float4* sWe4 = reinterpret_cast<float4*>(sWe);

    // Phase-1 mapping: thread t owns chunks of k-row (t>>3), slot (t&7).
    // float4 indices: k*25 + slot + {0,8,16}, plus k*25+24 for slot==0.
    const int k1   = t >> 3;
    const int slot = t & 7;
    const int i0   = k1 * 25 + slot;
    const bool x4  = (slot == 0);

    const int d = t >> 1;
    const int half = t & 1;
    const bool dt = (t < 2 * D);           // 200 worker threads, phases 3/4

    float pbout = 0.f;
    if (dt && !half) pbout = bout[d];      // loop-invariant

    int n = blockIdx.x;

    // ---- initial prefetch of row n ----
    float4 pa0, pa1, pa2, pa3, pb0, pb1, pb2, pb3;
    float pitem = 0.f;
    int   padj  = 0;
    {
        const float4* e4 = reinterpret_cast<const float4*>(ent + (size_t)n * KD);
        const float4* w4 = reinterpret_cast<const float4*>(wr  + (size_t)n * KD);
        pa0 = e4[i0];      pb0 = w4[i0];
        pa1 = e4[i0 + 8];  pb1 = w4[i0 + 8];
        pa2 = e4[i0 + 16]; pb2 = w4[i0 + 16];
        if (x4) { pa3 = e4[i0 + 24]; pb3 = w4[i0 + 24]; }
        if (t < K)        padj  = adj[(size_t)n * K + t];
        if (dt && !half)  pitem = item[(size_t)n * D + d];
    }

    for (;;) {
        // ---- phase 1: We -> LDS, per-lane partial k-sum, shfl reduce ----
        float s;
        {
            float4 p;
            p.x = pa0.x * pb0.x; p.y = pa0.y * pb0.y;
            p.z = pa0.z * pb0.z; p.w = pa0.w * pb0.w;
            sWe4[i0] = p;
            s = (p.x + p.y) + (p.z + p.w);
            p.x = pa1.x * pb1.x; p.y = pa1.y * pb1.y;
            p.z = pa1.z * pb1.z; p.w = pa1.w * pb1.w;
            sWe4[i0 + 8] = p;
            s += (p.x + p.y) + (p.z + p.w);
            p.x = pa2.x * pb2.x; p.y = pa2.y * pb2.y;
            p.z = pa2.z * pb2.z; p.w = pa2.w * pb2.w;
            sWe4[i0 + 16] = p;
            s += (p.x + p.y) + (p.z + p.w);
            if (x4) {
                p.x = pa3.x * pb3.x; p.y = pa3.y * pb3.y;
                p.z = pa3.z * pb3.z; p.w = pa3.w * pb3.w;
                sWe4[i0 + 24] = p;
                s += (p.x + p.y) + (p.z + p.w);
            }
        }
        s += __shfl_xor(s, 1);
        s += __shfl_xor(s, 2);
        s += __shfl_xor(s, 4);
        if (x4) sSum[k1] = s;

        // ---- issue prefetch for NEXT row (stays in flight across barriers) ----
        const int n2 = n + NBLK;
        const bool more = (n2 < N);
        float nitem = 0.f;
        int   nadj  = 0;
        if (more) {
            const float4* e4 = reinterpret_cast<const float4*>(ent + (size_t)n2 * KD);
            const float4* w4 = reinterpret_cast<const float4*>(wr  + (size_t)n2 * KD);
            pa0 = e4[i0];      pb0 = w4[i0];
            pa1 = e4[i0 + 8];  pb1 = w4[i0 + 8];
            pa2 = e4[i0 + 16]; pb2 = w4[i0 + 16];
            if (x4) { pa3 = e4[i0 + 24]; pb3 = w4[i0 + 24]; }
            if (t < K)        nadj  = adj[(size_t)n2 * K + t];
            if (dt && !half)  nitem = item[(size_t)n2 * D + d];
        }
        ldsbar();   // sync1: sWe + sSum ready (no vmcnt drain!)

        // ---- phase 2: leaky-relu + mask + softmax over K (wave 0) ----
        if (t < K) {
            float sv = sSum[t];
            float e  = sv > 0.f ? sv : ALPHA * sv;
            float lg = padj > 0 ? e : NEG_INF;
            float m = lg;
            #pragma unroll
            for (int off = 16; off; off >>= 1)
                m = fmaxf(m, __shfl_xor(m, off, 32));
            float p = expf(lg - m);
            float sm = p;
            #pragma unroll
            for (int off = 16; off; off >>= 1)
                sm += __shfl_xor(sm, off, 32);
            sAtt[t] = p / sm;
        }
        ldsbar();   // sync2: sAtt ready

        // ---- phase 3: h[d] = sum_k att[k]*We[k][d], split-K over lane pairs ----
        if (dt) {
            const int k0 = half * 16;
            float h = 0.f;
            #pragma unroll
            for (int kk = 0; kk < 16; ++kk)
                h = fmaf(sAtt[k0 + kk], sWe[(k0 + kk) * D + d], h);
            h += __shfl_xor(h, 1);
            if (!half) sH[d] = h;
        }
        ldsbar();   // sync3: sH ready

        // ---- phase 4: out[d] = h . Wout[d,:] + b[d] + item[d], split-J ----
        if (dt) {
            const float* wrow = Wout + (size_t)d * D + half * 50;
            const float* hh   = sH + half * 50;
            float acc = 0.f;
            #pragma unroll
            for (int j = 0; j < 50; ++j)
                acc = fmaf(hh[j], wrow[j], acc);
            acc += __shfl_xor(acc, 1);
            if (!half) out[(size_t)n * D + d] = acc + pbout + pitem;
        }

        if (!more) break;
        n = n2;
        pitem = nitem;
        padj  = nadj;
        // next iteration's phase 1 reads the new LDS contents; barrier before
        // overwrite is sync3 above (phase 3 already consumed sWe, phase 4 only
        // reads sH -- but phase-1 writes of iter i+1 could race phase-4 reads
        // of sH? No: sH is a separate buffer; sWe overwrite races phase-3 of
        // SAME iter only, which sync3 orders. sAtt/sSum overwrites are ordered
        // by sync1 of the next iter... sSum written in next phase-1 races
        // phase-2 read? phase-2 of iter i read sSum before sync2; next write
        // is after sync3 > sync2. Safe.
        ldsbar();   // sync4: protect sWe/sSum overwrite vs phase-3/4 readers
    }
}

extern "C" void kernel_launch(void* const* d_in, const int* in_sizes, int n_in,
                              void* d_out, int out_size, void* d_ws, size_t ws_size,
                              hipStream_t stream) {
    const float* item = (const float*)d_in[0];
    const float* ent  = (const float*)d_in[1];
    const float* wr   = (const float*)d_in[2];
    const int*   adj  = (const int*)d_in[3];
    const float* Wout = (const float*)d_in[4];
    const float* bout = (const float*)d_in[5];
    float* out = (float*)d_out;

    const int N = 40000;
    gat_fused_pipe<<<NBLK, 256, 0, stream>>>(item, ent, wr, adj, Wout, bout, out, N);
}

// Round 4
// 312.713 us; speedup vs baseline: 1.4403x; 1.0330x over previous
//
#include <hip/hip_runtime.h>

#define NEG_INF -9e15f
#define ALPHA 0.2f

// Wave-per-row design: each 64-lane wave owns one row stream end-to-end.
// No __syncthreads anywhere (same-wave DS ops are processed in order by the
// DS pipe; LDS regions are per-wave). 768 blocks x 4 waves = 3072 streams,
// LDS 51.2KB/block -> 3 blocks/CU. Phase 4 reads WoutT (transposed by a tiny
// prelude kernel into d_ws) so global reads are lane-consecutive (coalesced)
// instead of a 64-cache-line scatter.
constexpr int K = 32, D = 100, KD = K * D;     // 3200 floats, 800 float4
constexpr int NBLK = 768;                      // 3 blocks/CU
constexpr int WPB = 4;                         // waves per block
constexpr int NSTREAM = NBLK * WPB;            // 3072 row streams

__global__ __launch_bounds__(256) void transpose_wout(
    const float* __restrict__ W, float* __restrict__ WT)
{
    int idx = blockIdx.x * 256 + threadIdx.x;
    if (idx < D * D) {
        int j = idx / D, d = idx - j * D;
        WT[idx] = W[d * D + j];    // WT[j][d] = W[d][j]
    }
}

__global__ __launch_bounds__(256) void gat_wave_row(
    const float* __restrict__ item,   // [N, D]
    const float* __restrict__ ent,    // [N, K, D]
    const float* __restrict__ wr,     // [N, K, D]
    const int*   __restrict__ adj,    // [N, K]
    const float* __restrict__ WT,     // [D, D] transposed Wout (in ws)
    const float* __restrict__ bout,   // [D]
    float* __restrict__ out,          // [N, D]
    int N)
{
    __shared__ float4 sWe4[WPB * (KD / 4)];   // 51200 B, per-wave regions

    const int t   = threadIdx.x;
    const int wid = t >> 6;
    const int l   = t & 63;
    const int k   = l & 31;          // k-row this lane reduces
    const int h   = l >> 5;          // which half of the k-row
    const bool bl = (l < 36);        // lanes owning d = 64+l outputs
    const int lb  = bl ? l : 35;     // clamped to keep reads in range

    float4* we4 = sWe4 + wid * (KD / 4);
    const float* we = reinterpret_cast<const float*>(we4);

    const float bouta = bout[l];
    const float boutb = bout[64 + lb];

    for (int n = blockIdx.x * WPB + wid; n < N; n += NSTREAM) {
        const float4* e4 = reinterpret_cast<const float4*>(ent + (size_t)n * KD);
        const float4* w4 = reinterpret_cast<const float4*>(wr  + (size_t)n * KD);

        // ---- coalesced loads: 12 full-wave float4 rounds + half-wave tail ----
        float4 a[12], b[12], at, bt;
        #pragma unroll
        for (int j = 0; j < 12; ++j) { a[j] = e4[l + 64 * j]; b[j] = w4[l + 64 * j]; }
        if (l < 32) { at = e4[768 + l]; bt = w4[768 + l]; }
        const int   adjv = adj[(size_t)n * K + k];
        const float itma = item[(size_t)n * D + l];
        const float itmb = item[(size_t)n * D + 64 + lb];

        // ---- multiply, stage We into per-wave LDS ----
        #pragma unroll
        for (int j = 0; j < 12; ++j) {
            float4 p;
            p.x = a[j].x * b[j].x; p.y = a[j].y * b[j].y;
            p.z = a[j].z * b[j].z; p.w = a[j].w * b[j].w;
            we4[l + 64 * j] = p;
        }
        if (l < 32) {
            float4 p;
            p.x = at.x * bt.x; p.y = at.y * bt.y;
            p.z = at.z * bt.z; p.w = at.w * bt.w;
            we4[768 + l] = p;
        }

        // ---- k-sum: lane (k,h) reads its half of k-row; b128 conflict-free ----
        float s = 0.f;
        {
            const float4* base = we4 + k * 25 + h * 13;   // h=0: c4 0..12, h=1: 13..24
            #pragma unroll
            for (int j = 0; j < 12; ++j) {
                float4 q = base[j];
                s += (q.x + q.y) + (q.z + q.w);
            }
            if (h == 0) {
                float4 q = base[12];
                s += (q.x + q.y) + (q.z + q.w);
            }
        }
        s += __shfl_xor(s, 32);     // combine halves -> every lane has sum[k]

        // ---- softmax over K, fully in registers (width-32 groups) ----
        float e  = s > 0.f ? s : ALPHA * s;
        float lg = adjv > 0 ? e : NEG_INF;
        float m = lg;
        #pragma unroll
        for (int off = 16; off; off >>= 1)
            m = fmaxf(m, __shfl_xor(m, off, 32));
        float p = expf(lg - m);
        float sm = p;
        #pragma unroll
        for (int off = 16; off; off >>= 1)
            sm += __shfl_xor(sm, off, 32);
        const float att = p / sm;   // lane holds att[k=l&31]

        // ---- phase 3: h[d] = sum_k att[k] * We[k][d]; lane owns d=l, 64+l ----
        float ha = 0.f, hb = 0.f;
        #pragma unroll
        for (int kk = 0; kk < K; ++kk) {
            float ak = __shfl(att, kk);           // broadcast att[kk]
            ha = fmaf(ak, we[kk * D + l], ha);
            hb = fmaf(ak, we[kk * D + 64 + lb], hb);
        }

        // ---- phase 4: out[d] = sum_j h[j]*WT[j][d] + b[d] + item[d] ----
        float aa = 0.f, ab = 0.f;
        #pragma unroll 4
        for (int j = 0; j < 64; ++j) {
            float hj = __shfl(ha, j);
            aa = fmaf(hj, WT[j * D + l], aa);
            ab = fmaf(hj, WT[j * D + 64 + lb], ab);
        }
        #pragma unroll 4
        for (int j = 0; j < 36; ++j) {
            float hj = __shfl(hb, j);             // sources lanes 0..35 only
            aa = fmaf(hj, WT[(64 + j) * D + l], aa);
            ab = fmaf(hj, WT[(64 + j) * D + 64 + lb], ab);
        }

        out[(size_t)n * D + l] = aa + bouta + itma;
        if (bl) out[(size_t)n * D + 64 + l] = ab + boutb + itmb;
    }
}

extern "C" void kernel_launch(void* const* d_in, const int* in_sizes, int n_in,
                              void* d_out, int out_size, void* d_ws, size_t ws_size,
                              hipStream_t stream) {
    const float* item = (const float*)d_in[0];
    const float* ent  = (const float*)d_in[1];
    const float* wr   = (const float*)d_in[2];
    const int*   adj  = (const int*)d_in[3];
    const float* Wout = (const float*)d_in[4];
    const float* bout = (const float*)d_in[5];
    float* out  = (float*)d_out;
    float* WT   = (float*)d_ws;    // 40000 B scratch for transposed Wout

    const int N = 40000;
    transpose_wout<<<(D * D + 255) / 256, 256, 0, stream>>>(Wout, WT);
    gat_wave_row<<<NBLK, 256, 0, stream>>>(item, ent, wr, adj, WT, bout, out, N);
}